// Round 15
// baseline (483.396 us; speedup 1.0000x reference)
//
#include <hip/hip_runtime.h>
#include <stdint.h>

typedef unsigned short u16;
typedef unsigned int u32;
typedef __attribute__((ext_vector_type(8))) short s16x8;
typedef __attribute__((ext_vector_type(4))) float f32x4;

__device__ __forceinline__ float bf2f(u16 u) {
    return __builtin_bit_cast(float, (u32)u << 16);
}
__device__ __forceinline__ u16 f2bf(float f) {
    u32 u = __builtin_bit_cast(u32, f);
    u += 0x7FFFu + ((u >> 16) & 1u);
    return (u16)(u >> 16);
}
__device__ __forceinline__ void unpk4(uint2 r, float* o) {
    o[0] = bf2f((u16)(r.x & 0xffff)); o[1] = bf2f((u16)(r.x >> 16));
    o[2] = bf2f((u16)(r.y & 0xffff)); o[3] = bf2f((u16)(r.y >> 16));
}

// async global->LDS, 16 bytes per lane. LDS dest must be linear in lane order.
__device__ __forceinline__ void gl16(const u16* g, u16* l) {
    __builtin_amdgcn_global_load_lds(
        (const __attribute__((address_space(1))) u32*)(const void*)g,
        (__attribute__((address_space(3))) u32*)(void*)l, 16, 0, 0);
}

#define BAR() { __builtin_amdgcn_sched_barrier(0); __builtin_amdgcn_s_barrier(); __builtin_amdgcn_sched_barrier(0); }

// ---------------------------------------------------------------------------
// 256x256 conv GEMM — interleaved counted-vmcnt schedule (R13, 85.6us).
// ---------------------------------------------------------------------------
template<int DIL>
__global__ __launch_bounds__(512) void conv8_k(
    const u16* __restrict__ Apad, const u16* __restrict__ Bw,
    u16* __restrict__ Cb0, u16* __restrict__ Cb1)
{
    __shared__ u16 sA[2][16384];
    __shared__ u16 sB[2][16384];
    const int tid  = threadIdx.x;
    const int wid  = tid >> 6;
    const int lane = tid & 63;
    const int wr = (wid >> 2) * 128;
    const int wc = (wid & 3) * 64;
    const int lr = lane & 15;
    const int kq = lane >> 4;
    const int batch = blockIdx.x >> 3;
    const int m0b   = (blockIdx.x & 7) * 256;
    const int bn0   = blockIdx.y * 256;
    const int kbeg  = blockIdx.z * 2560;
    const u16* Ab = Apad + (long)batch * 2056 * 1024;

    const int row0 = tid >> 3;
    const int g0   = (tid & 7) ^ (row0 & 7);

    f32x4 acc[8][4] = {};
    s16x8 aF[4][2], bF[4][2];

    auto stageA2 = [&](int nb, int kt, int c) {
        const int ktabs = kbeg + kt * 64;
        const int tap = ktabs >> 10;
        const long rbase = (long)(8 + m0b + c * 64 + (tap - 4) * DIL) * 1024
                           + (ktabs & 1023) + g0 * 8;
        u16* dst = &sA[nb][(c * 64) * 64 + tid * 8];
        gl16(Ab + rbase + (long)row0 * 1024, dst);
        gl16(Ab + rbase + (long)(row0 + 128) * 1024, dst + 8192);
    };
    auto stageB = [&](int nb, int kt, int h) {
        const int ktabs = kbeg + kt * 64;
        const long rbase = (long)(bn0 + h * 128) * 5120 + ktabs + g0 * 8;
        u16* dst = &sB[nb][h * 8192 + tid * 8];
        gl16(Bw + rbase + (long)row0 * 5120, dst);
        gl16(Bw + rbase + (long)(row0 + 64) * 5120, dst + 4096);
    };
    auto readA = [&](int nb, int mq) {
        #pragma unroll
        for (int m = 0; m < 4; m++) {
            const int row = wr + (mq * 4 + m) * 16 + lr;
            #pragma unroll
            for (int ks = 0; ks < 2; ks++) {
                const int chunk = ks * 4 + kq;
                aF[m][ks] = *(const s16x8*)&sA[nb][row * 64 + ((chunk ^ (row & 7)) << 3)];
            }
        }
    };
    auto readB4 = [&](int nb, int nq) {
        #pragma unroll
        for (int n = 0; n < 2; n++) {
            const int row = wc + (nq * 2 + n) * 16 + lr;
            #pragma unroll
            for (int ks = 0; ks < 2; ks++) {
                const int chunk = ks * 4 + kq;
                bF[nq * 2 + n][ks] = *(const s16x8*)&sB[nb][row * 64 + ((chunk ^ (row & 7)) << 3)];
            }
        }
    };

#define MFQ(MQ, NQ) \
    { __builtin_amdgcn_s_setprio(1); \
      _Pragma("unroll") \
      for (int m = 0; m < 4; m++) { \
        _Pragma("unroll") \
        for (int n = 0; n < 2; n++) { \
          _Pragma("unroll") \
          for (int ks = 0; ks < 2; ks++) \
            acc[(MQ)*4+m][(NQ)*2+n] = __builtin_amdgcn_mfma_f32_16x16x32_bf16( \
                aF[m][ks], bF[(NQ)*2+n][ks], acc[(MQ)*4+m][(NQ)*2+n], 0, 0, 0); \
        } } \
      __builtin_amdgcn_s_setprio(0); }

    stageB(0, 0, 0); stageB(0, 0, 1); stageA2(0, 0, 0); stageA2(0, 0, 1);

    const int NT = 40;
    for (int t = 0; t < NT; ++t) {
        const int nb = t & 1;
        asm volatile("s_waitcnt vmcnt(2)" ::: "memory");
        BAR();
        readB4(nb, 0); readB4(nb, 1); readA(nb, 0);
        if (t + 1 < NT) stageB(nb ^ 1, t + 1, 0);
        MFQ(0, 0);
        if (t + 1 < NT) stageB(nb ^ 1, t + 1, 1);
        MFQ(0, 1);
        if (t + 1 < NT) { asm volatile("s_waitcnt vmcnt(4)" ::: "memory"); }
        else            { asm volatile("s_waitcnt vmcnt(0)" ::: "memory"); }
        BAR();
        readA(nb, 1);
        if (t + 1 < NT) stageA2(nb ^ 1, t + 1, 0);
        MFQ(1, 0);
        if (t + 1 < NT) stageA2(nb ^ 1, t + 1, 1);
        MFQ(1, 1);
    }
#undef MFQ

    u16* C = (blockIdx.z ? Cb1 : Cb0) + (long)batch * 2048 * 1024;
    #pragma unroll
    for (int m = 0; m < 8; m++) {
        #pragma unroll
        for (int n = 0; n < 4; n++) {
            const int cc = bn0 + wc + n * 16 + lr;
            #pragma unroll
            for (int j = 0; j < 4; j++) {
                const int r = m0b + wr + m * 16 + kq * 4 + j;
                C[(long)r * 1024 + cc] = f2bf(acc[m][n][j]);
            }
        }
    }
}

// ---------------------------------------------------------------------------
// bf16 MFMA GEMM (m97 staging). Tile 128 x TN, BK=32, 4 waves, 16x16x32 MFMA.
// EPI: 0 bf16 C; 1 f32 C; 2 gated residual (f32+bf16); 5 gated res (f32 only);
//      6 gated residual, bf16 res in (res reinterpreted as u16*) + bf16 out
// KS>1: bf16 partials to Pp (elems; slice stride pStride).
// ---------------------------------------------------------------------------
template<int AL, int BL, int EPI, int TN, int KS, int SWZ>
__global__ __launch_bounds__(256) void gemm_bf16(
    const u16* __restrict__ A, const u16* __restrict__ B,
    float* __restrict__ Cf, u16* __restrict__ Cb,
    const float* __restrict__ res, const float* __restrict__ gate,
    int M, int N, int K, int lda, int ldb,
    long aBS, long bBS, long cBS,
    u16* __restrict__ Pp, long pStride, int nby)
{
    constexpr int NFRAG = TN / 32;
    __shared__ u16 sA[128 * 32];
    __shared__ u16 sB[TN * 32];
    const int tid  = threadIdx.x;
    const int lane = tid & 63;
    const int wave = tid >> 6;
    const int wr = (wave >> 1) * 64;
    const int wc = (wave & 1) * (TN / 2);

    int bidx, bidy;
    if (SWZ) {
        const int nb  = gridDim.x;
        const int cpx = nb >> 3;
        const int bf  = blockIdx.x;
        const int sw  = (bf & 7) * cpx + (bf >> 3);
        bidx = sw / nby; bidy = sw - bidx * nby;
    } else {
        bidx = blockIdx.x; bidy = blockIdx.y;
    }
    const int m0 = bidx * 128;
    const int n0 = bidy * TN;
    const int zz = blockIdx.z;
    const long bz = (KS > 1) ? (zz / KS) : zz;
    const int ks  = (KS > 1) ? (zz % KS) : 0;
    const u16* Ab = A + bz * aBS;
    const u16* Bb = B + bz * bBS;

    f32x4 acc[4][NFRAG] = {};
    const int lr = lane & 15;
    const int lk = (lane >> 4) << 3;
    const int ar0 = tid >> 2;
    const int akg = (tid & 3) << 3;

    const int Kp = K / KS;
    const int kbeg = ks * Kp, kend = kbeg + Kp;

    for (int kk = kbeg; kk < kend; kk += 32) {
        __syncthreads();
        if (AL == 0) {
            gl16(Ab + (long)(m0 + ar0) * lda + kk + akg,      sA + tid * 8);
            gl16(Ab + (long)(m0 + ar0 + 64) * lda + kk + akg, sA + tid * 8 + 2048);
        } else {     // AL==1: A^T source, strided gather
            for (int t = tid; t < 512; t += 256) {
                int row = t & 127, kg = (t >> 7) << 3;
                u32 w0[4];
                #pragma unroll
                for (int j2 = 0; j2 < 4; j2++) {
                    u16 lo = Ab[(long)(kk + kg + 2*j2    ) * lda + m0 + row];
                    u16 hi = Ab[(long)(kk + kg + 2*j2 + 1) * lda + m0 + row];
                    w0[j2] = (u32)lo | ((u32)hi << 16);
                }
                uint4 v; v.x = w0[0]; v.y = w0[1]; v.z = w0[2]; v.w = w0[3];
                *reinterpret_cast<uint4*>(sA + row * 32 + kg) = v;
            }
        }
        if (BL == 1) {
            gl16(Bb + (long)(n0 + ar0) * ldb + kk + akg, sB + tid * 8);
            if (TN == 128)
                gl16(Bb + (long)(n0 + ar0 + 64) * ldb + kk + akg, sB + tid * 8 + 2048);
        } else {
            for (int t = tid; t < TN * 4; t += 256) {
                int col = t & (TN - 1), kg = (t / TN) << 3;
                u32 w0[4];
                #pragma unroll
                for (int j2 = 0; j2 < 4; j2++) {
                    u16 lo = Bb[(long)(kk + kg + 2*j2    ) * ldb + n0 + col];
                    u16 hi = Bb[(long)(kk + kg + 2*j2 + 1) * ldb + n0 + col];
                    w0[j2] = (u32)lo | ((u32)hi << 16);
                }
                uint4 v; v.x = w0[0]; v.y = w0[1]; v.z = w0[2]; v.w = w0[3];
                *reinterpret_cast<uint4*>(sB + col * 32 + kg) = v;
            }
        }
        __syncthreads();
        s16x8 aF[4], bF[NFRAG];
        #pragma unroll
        for (int m = 0; m < 4; m++)
            aF[m] = *reinterpret_cast<const s16x8*>(sA + (wr + m*16 + lr) * 32 + lk);
        #pragma unroll
        for (int n = 0; n < NFRAG; n++)
            bF[n] = *reinterpret_cast<const s16x8*>(sB + (wc + n*16 + lr) * 32 + lk);
        #pragma unroll
        for (int m = 0; m < 4; m++)
            #pragma unroll
            for (int n = 0; n < NFRAG; n++)
                acc[m][n] = __builtin_amdgcn_mfma_f32_16x16x32_bf16(aF[m], bF[n], acc[m][n], 0, 0, 0);
    }

    const int rj = (lane >> 4) << 2;
    if (KS > 1) {
        u16* Pb = Pp + (long)ks * pStride + bz * cBS;
        #pragma unroll
        for (int m = 0; m < 4; m++)
            #pragma unroll
            for (int n = 0; n < NFRAG; n++) {
                const int cc = n0 + wc + n*16 + lr;
                #pragma unroll
                for (int j = 0; j < 4; j++) {
                    const int r = m0 + wr + m*16 + rj + j;
                    Pb[(long)r * N + cc] = f2bf(acc[m][n][j]);
                }
            }
        return;
    }

    float* Cfb = Cf + bz * cBS;
    #pragma unroll
    for (int m = 0; m < 4; m++) {
        #pragma unroll
        for (int n = 0; n < NFRAG; n++) {
            const int cc = n0 + wc + n*16 + lr;
            #pragma unroll
            for (int j = 0; j < 4; j++) {
                const int r = m0 + wr + m*16 + rj + j;
                const long idx = (long)r * N + cc;
                const float v = acc[m][n][j];
                if (EPI == 0) {
                    Cb[bz * cBS + idx] = f2bf(v);
                } else if (EPI == 1) {
                    Cfb[idx] = v;
                } else if (EPI == 6) {
                    float o = bf2f(reinterpret_cast<const u16*>(res)[idx]) + gate[r] * v;
                    Cb[idx] = f2bf(o);
                } else {   // 2 or 5: gated residual, f32 res
                    float o = res[idx] + gate[r] * v;
                    Cfb[idx] = o;
                    if (EPI == 2) Cb[idx] = f2bf(o);
                }
            }
        }
    }
}

// split-K combine over bf16 partials; BF=1 -> bf16 out, else f32 out
template<int KS, int BF>
__global__ __launch_bounds__(256) void ksum_k(
    const u16* __restrict__ Pp, long pStride,
    float* __restrict__ outf, u16* __restrict__ outb, int n4)
{
    int i = blockIdx.x * 256 + threadIdx.x;
    if (i >= n4) return;
    float s[4] = {0.f, 0.f, 0.f, 0.f};
    #pragma unroll
    for (int k = 0; k < KS; k++) {
        uint2 r = reinterpret_cast<const uint2*>(Pp + (long)k * pStride)[i];
        float v[4]; unpk4(r, v);
        s[0] += v[0]; s[1] += v[1]; s[2] += v[2]; s[3] += v[3];
    }
    if (BF) {
        u32 lo = (u32)f2bf(s[0]) | ((u32)f2bf(s[1]) << 16);
        u32 hi = (u32)f2bf(s[2]) | ((u32)f2bf(s[3]) << 16);
        reinterpret_cast<uint2*>(outb)[i] = make_uint2(lo, hi);
    } else {
        float4 o; o.x = s[0]; o.y = s[1]; o.z = s[2]; o.w = s[3];
        reinterpret_cast<float4*>(outf)[i] = o;
    }
}

// ---------------------------------------------------------------------------
// Mega-prep: zero-init, converts (incl. Wq_ltm bf16), transposes, CW, WC.
// ---------------------------------------------------------------------------
__global__ __launch_bounds__(256) void prep_k(
    const float* __restrict__ x, const float* __restrict__ cache,
    const float* __restrict__ wm_keys, const float* __restrict__ wm,
    const float* __restrict__ Wo_wm, const float* __restrict__ Wq_wm,
    const float* __restrict__ Wq_ltm, const float* __restrict__ Wqw_wm,
    const float* __restrict__ Ww_wm, const float* __restrict__ Wqw_ltm,
    const float* __restrict__ Ww_ltm, const float* __restrict__ Wo_ltm,
    const float* __restrict__ conv1_w, const float* __restrict__ conv2_w,
    u16* __restrict__ xpad1, u16* __restrict__ xpad2,
    float* __restrict__ totl,
    u16* __restrict__ act0, u16* __restrict__ cache_b, u16* __restrict__ keys_b,
    u16* __restrict__ Wqb, u16* __restrict__ WbigT,
    u16* __restrict__ WoLt, u16* __restrict__ c1wt, u16* __restrict__ c2wt,
    u16* __restrict__ cache_t, float* __restrict__ CW, float* __restrict__ WC)
{
    __shared__ float tile[32][33];
    int b = blockIdx.x;
    int tid = threadIdx.x;

    if (b < 64) {
        int i = b * 256 + tid;
        int bt = i >> 12, j = i & 4095;
        long offp = (long)bt * (2056L * 1024 / 2) + j;
        reinterpret_cast<u32*>(xpad1)[offp] = 0u;
        reinterpret_cast<u32*>(xpad2)[offp] = 0u;
        if (i < 3072) totl[i] = 0.f;
        return;
    }
    b -= 64;
    if (b < 9218) {
        const float* in; u16* out; int i;
        if (b < 8192)      { in = x;       out = act0;    i = b * 256 + tid; }
        else if (b < 8960) { in = cache;   out = cache_b; i = (b - 8192) * 256 + tid; }
        else if (b < 8962) { in = wm_keys; out = keys_b;  i = (b - 8960) * 256 + tid; }
        else               { in = Wq_ltm;  out = Wqb;     i = (b - 8962) * 256 + tid; }
        float4 v = reinterpret_cast<const float4*>(in)[i];
        u32 lo = (u32)f2bf(v.x) | ((u32)f2bf(v.y) << 16);
        u32 hi = (u32)f2bf(v.z) | ((u32)f2bf(v.w) << 16);
        reinterpret_cast<uint2*>(out)[i] = make_uint2(lo, hi);
        return;
    }
    b -= 9218;
    if (b < 12288) {
        const float* in; u16* out; int R, C, l;
        if (b < 1024) {
            l = b & 255; R = 1024; C = 256;
            int m = b >> 8;
            if      (m == 0) { in = Wqw_wm;  out = WbigT; }
            else if (m == 1) { in = Ww_wm;   out = WbigT + 262144; }
            else if (m == 2) { in = Wqw_ltm; out = WbigT + 524288; }
            else             { in = Ww_ltm;  out = WbigT + 786432; }
        } else if (b < 1280) {
            l = b - 1024; in = Wo_ltm; out = WoLt; R = 256; C = 1024;
        } else if (b < 6400) {
            l = b - 1280; in = conv1_w; out = c1wt; R = 5120; C = 1024;
        } else if (b < 11520) {
            l = b - 6400; in = conv2_w; out = c2wt; R = 5120; C = 1024;
        } else {
            int lb = b - 11520;
            int z = lb / 192; l = lb % 192;
            in = cache + (long)z * 196608; out = cache_t + (long)z * 196608;
            R = 768; C = 256;
        }
        const int ct = C >> 5;
        const int c0 = (l % ct) * 32, r0 = (l / ct) * 32;
        int tx = tid & 31, ty = tid >> 5;
        #pragma unroll
        for (int i = 0; i < 32; i += 8)
            tile[ty + i][tx] = in[(long)(r0 + ty + i) * C + c0 + tx];
        __syncthreads();
        #pragma unroll
        for (int i = 0; i < 32; i += 8)
            out[(long)(c0 + ty + i) * R + r0 + tx] = f2bf(tile[tx][ty + i]);
        return;
    }
    b -= 12288;
    if (b < 32) {
        const float* wrow = wm + (long)(b >> 3) * 2056 + (b & 7) * 257;
        int c = tid;
        float a0 = 0.f, a1 = 0.f, a2 = 0.f, a3 = 0.f;
        for (int dd = 0; dd < 256; dd++) {
            float w = wrow[dd];
            const float* wo = Wo_wm + (long)dd * 1024;
            a0 += w * wo[c]; a1 += w * wo[c + 256];
            a2 += w * wo[c + 512]; a3 += w * wo[c + 768];
        }
        float* o = CW + (long)b * 1024;
        o[c] = a0; o[c + 256] = a1; o[c + 512] = a2; o[c + 768] = a3;
        return;
    }
    b -= 32;
    {
        const float* wrow = wm + (long)(b >> 3) * 2056 + (b & 7) * 257;
        int c = tid;
        float a0 = 0.f, a1 = 0.f, a2 = 0.f, a3 = 0.f;
        for (int j = 0; j < 256; j++) {
            float w = wrow[j];
            a0 += Wq_wm[(long)(c      ) * 256 + j] * w;
            a1 += Wq_wm[(long)(c + 256) * 256 + j] * w;
            a2 += Wq_wm[(long)(c + 512) * 256 + j] * w;
            a3 += Wq_wm[(long)(c + 768) * 256 + j] * w;
        }
        float* o = WC + (long)b * 1024;
        o[c] = a0; o[c + 256] = a1; o[c + 512] = a2; o[c + 768] = a3;
    }
}

// gate = sigmoid(bf16_row . w)
__global__ __launch_bounds__(256) void gemv_sigmoid_k(
    const u16* __restrict__ X, const float* __restrict__ w,
    float* __restrict__ out)
{
    int row  = blockIdx.x * 4 + (threadIdx.x >> 6);
    int lane = threadIdx.x & 63;
    const u16* xr = X + (long)row * 1024;
    float s = 0.f;
    for (int i = lane * 4; i < 1024; i += 256) {
        uint2 r = *reinterpret_cast<const uint2*>(xr + i);
        float v[4]; unpk4(r, v);
        s += v[0]*w[i] + v[1]*w[i+1] + v[2]*w[i+2] + v[3]*w[i+3];
    }
    #pragma unroll
    for (int o = 32; o > 0; o >>= 1) s += __shfl_down(s, o);
    if (lane == 0) out[row] = 1.f / (1.f + __expf(-s));
}

// softmax over 768 bf16 scores (scale 1/16), summing KS bf16 partial slices
template<int KS>
__global__ __launch_bounds__(256) void softmax768_k(
    const u16* __restrict__ scores, long pStride, u16* __restrict__ out,
    const float* __restrict__ gate)
{
    __shared__ float s4[4], s4b[4];
    int row = blockIdx.x;
    int t = threadIdx.x;
    const u16* sr = scores + (long)row * 768;
    float v[3];
    float m = -1e30f;
    #pragma unroll
    for (int i = 0; i < 3; i++) {
        float sv = bf2f(sr[t + i*256]);
        #pragma unroll
        for (int k = 1; k < KS; k++) sv += bf2f(sr[(long)k * pStride + t + i*256]);
        v[i] = sv * 0.0625f; m = fmaxf(m, v[i]);
    }
    float wm_ = m;
    #pragma unroll
    for (int o = 32; o > 0; o >>= 1) wm_ = fmaxf(wm_, __shfl_down(wm_, o));
    if ((t & 63) == 0) s4[t >> 6] = wm_;
    __syncthreads();
    float bm = fmaxf(fmaxf(s4[0], s4[1]), fmaxf(s4[2], s4[3]));
    float sum = 0.f;
    #pragma unroll
    for (int i = 0; i < 3; i++) { v[i] = __expf(v[i] - bm); sum += v[i]; }
    #pragma unroll
    for (int o = 32; o > 0; o >>= 1) sum += __shfl_down(sum, o);
    if ((t & 63) == 0) s4b[t >> 6] = sum;
    __syncthreads();
    float bs = s4b[0] + s4b[1] + s4b[2] + s4b[3];
    float g = gate ? gate[row] : 1.0f;
    float inv = g / bs;
    u16* orow = out + (long)row * 768;
    #pragma unroll
    for (int i = 0; i < 3; i++) orow[t + i*256] = f2bf(v[i] * inv);
}

// Fused WM-read v4: bf16 x_ltm in, gate dot folded, writes ONLY padded xpad1.
__global__ __launch_bounds__(256) void wm_read_fused_k(
    const float* __restrict__ WC, const float* __restrict__ CW,
    const float* __restrict__ wg, const u16* __restrict__ xltm,
    u16* __restrict__ outb)
{
    __shared__ float sred[8][4];
    __shared__ float sg4[4];
    __shared__ float sa[8];
    __shared__ float gsh;
    int row = blockIdx.x;
    int b = row >> 11;
    int d = threadIdx.x, lane = d & 63, wave = d >> 6;
    long orow = (long)row * 1024;
    float rv[4];
    rv[0] = bf2f(xltm[orow + d]);
    rv[1] = bf2f(xltm[orow + d + 256]);
    rv[2] = bf2f(xltm[orow + d + 512]);
    rv[3] = bf2f(xltm[orow + d + 768]);
    float gp = rv[0] * wg[d] + rv[1] * wg[d + 256] + rv[2] * wg[d + 512] + rv[3] * wg[d + 768];
    #pragma unroll
    for (int o = 32; o > 0; o >>= 1) gp += __shfl_down(gp, o);
    if (lane == 0) sg4[wave] = gp;
    const float* wcb = WC + (long)b * 8192;
    #pragma unroll
    for (int k = 0; k < 8; k++) {
        const float* w = wcb + k * 1024;
        float v = rv[0] * w[d] + rv[1] * w[d + 256] + rv[2] * w[d + 512] + rv[3] * w[d + 768];
        #pragma unroll
        for (int o = 32; o > 0; o >>= 1) v += __shfl_down(v, o);
        if (lane == 0) sred[k][wave] = v;
    }
    __syncthreads();
    if (d < 8) sa[d] = (sred[d][0] + sred[d][1] + sred[d][2] + sred[d][3]) * 0.0625f;
    if (d == 0) gsh = 1.f / (1.f + __expf(-(sg4[0] + sg4[1] + sg4[2] + sg4[3])));
    __syncthreads();
    float m = sa[0];
    #pragma unroll
    for (int k = 1; k < 8; k++) m = fmaxf(m, sa[k]);
    float e[8], sum = 0.f;
    #pragma unroll
    for (int k = 0; k < 8; k++) { e[k] = __expf(sa[k] - m); sum += e[k]; }
    float inv = 1.f / sum;
    #pragma unroll
    for (int k = 0; k < 8; k++) e[k] *= inv;
    float g = gsh;
    const float* cwb = CW + (long)b * 8192;
    long prow = ((long)(row >> 11) * 2056 + 8 + (row & 2047)) * 1024;
    #pragma unroll
    for (int j = 0; j < 4; j++) {
        int c = d + j * 256;
        float acc = 0.f;
        #pragma unroll
        for (int k = 0; k < 8; k++) acc += e[k] * cwb[k * 1024 + c];
        outb[prow + c] = f2bf(rv[j] + g * acc);
    }
}

// conv1 combine: bf16 partials + gelu + residual from padded bf16; writes padded bf16 only
__global__ __launch_bounds__(256) void gelu_reduce_k(
    const u16* __restrict__ p0, const u16* __restrict__ p1,
    const u16* __restrict__ resp, const float* __restrict__ bias,
    u16* __restrict__ outp)
{
    int i4 = blockIdx.x * 256 + threadIdx.x;
    int r = i4 >> 8, c4 = (i4 & 255) << 2;
    long prow = ((long)(r >> 11) * 2056 + 8 + (r & 2047)) * 1024 + c4;
    float a[4], b[4], rr[4];
    unpk4(reinterpret_cast<const uint2*>(p0)[i4], a);
    unpk4(reinterpret_cast<const uint2*>(p1)[i4], b);
    unpk4(*reinterpret_cast<const uint2*>(resp + prow), rr);
    float4 bi = *reinterpret_cast<const float4*>(bias + c4);
    const float C0 = 0.79788456080286535588f, C1 = 0.044715f;
    float y0 = a[0] + b[0] + bi.x, y1 = a[1] + b[1] + bi.y;
    float y2 = a[2] + b[2] + bi.z, y3 = a[3] + b[3] + bi.w;
    float o0 = rr[0] + 0.5f * y0 * (1.f + tanhf(C0 * (y0 + C1 * y0 * y0 * y0)));
    float o1 = rr[1] + 0.5f * y1 * (1.f + tanhf(C0 * (y1 + C1 * y1 * y1 * y1)));
    float o2 = rr[2] + 0.5f * y2 * (1.f + tanhf(C0 * (y2 + C1 * y2 * y2 * y2)));
    float o3 = rr[3] + 0.5f * y3 * (1.f + tanhf(C0 * (y3 + C1 * y3 * y3 * y3)));
    u32 lo = (u32)f2bf(o0) | ((u32)f2bf(o1) << 16);
    u32 hi = (u32)f2bf(o2) | ((u32)f2bf(o3) << 16);
    *reinterpret_cast<uint2*>(outp + prow) = make_uint2(lo, hi);
}

// conv2 combine + gelu residual (from padded bf16) + layernorm -> f32 out + bf16 act
__global__ __launch_bounds__(256) void gelu_ln_k(
    const u16* __restrict__ p0, const u16* __restrict__ p1,
    const u16* __restrict__ resp, const float* __restrict__ bias,
    const float* __restrict__ g, const float* __restrict__ b,
    float* __restrict__ outf, u16* __restrict__ outb)
{
    __shared__ float rs[4], rss[4];
    int row = blockIdx.x, t = threadIdx.x;
    long i4 = (long)row * 256 + t;
    long prow = ((long)(row >> 11) * 2056 + 8 + (row & 2047)) * 1024 + (t << 2);
    float a[4], pb[4], rr[4];
    unpk4(reinterpret_cast<const uint2*>(p0)[i4], a);
    unpk4(reinterpret_cast<const uint2*>(p1)[i4], pb);
    unpk4(*reinterpret_cast<const uint2*>(resp + prow), rr);
    float4 bi = reinterpret_cast<const float4*>(bias)[t];
    const float C0 = 0.79788456080286535588f, C1 = 0.044715f;
    float y0 = a[0] + pb[0] + bi.x, y1 = a[1] + pb[1] + bi.y;
    float y2 = a[2] + pb[2] + bi.z, y3 = a[3] + pb[3] + bi.w;
    float o0 = rr[0] + 0.5f * y0 * (1.f + tanhf(C0 * (y0 + C1 * y0 * y0 * y0)));
    float o1 = rr[1] + 0.5f * y1 * (1.f + tanhf(C0 * (y1 + C1 * y1 * y1 * y1)));
    float o2 = rr[2] + 0.5f * y2 * (1.f + tanhf(C0 * (y2 + C1 * y2 * y2 * y2)));
    float o3 = rr[3] + 0.5f * y3 * (1.f + tanhf(C0 * (y3 + C1 * y3 * y3 * y3)));
    float s  = o0 + o1 + o2 + o3;
    float ss = o0*o0 + o1*o1 + o2*o2 + o3*o3;
    #pragma unroll
    for (int o = 32; o > 0; o >>= 1) { s += __shfl_down(s, o); ss += __shfl_down(ss, o); }
    if ((t & 63) == 0) { rs[t >> 6] = s; rss[t >> 6] = ss; }
    __syncthreads();
    float S = rs[0]+rs[1]+rs[2]+rs[3];
    float SS = rss[0]+rss[1]+rss[2]+rss[3];
    float mean = S * (1.f/1024.f);
    float var  = SS * (1.f/1024.f) - mean*mean;
    float rstd = rsqrtf(var + 1e-5f);
    float4 gg = reinterpret_cast<const float4*>(g)[t];
    float4 bv = reinterpret_cast<const float4*>(b)[t];
    float4 y;
    y.x = (o0-mean)*rstd*gg.x + bv.x;
    y.y = (o1-mean)*rstd*gg.y + bv.y;
    y.z = (o2-mean)*rstd*gg.z + bv.z;
    y.w = (o3-mean)*rstd*gg.w + bv.w;
    reinterpret_cast<float4*>(outf)[i4] = y;
    u32 lo = (u32)f2bf(y.x) | ((u32)f2bf(y.y) << 16);
    u32 hi = (u32)f2bf(y.z) | ((u32)f2bf(y.w) << 16);
    reinterpret_cast<uint2*>(outb)[i4] = make_uint2(lo, hi);
}

// Fused: both write-gates (bf16 LN row) + WM key attention.
__global__ __launch_bounds__(256) void attn8_wg_k(
    const u16* __restrict__ q, const u16* __restrict__ xo,
    const float* __restrict__ w1, const float* __restrict__ w2,
    const u16* __restrict__ keys, float* __restrict__ wD,
    float* __restrict__ gateb2)
{
    __shared__ float sred[8][4];
    __shared__ float sa[8];
    __shared__ float sg1[4], sg2[4];
    __shared__ float g1sh;
    int row = blockIdx.x;
    int d = threadIdx.x, lane = d & 63, wave = d >> 6;
    float qv = bf2f(q[(long)row * 1024 + d]);
    float xr[4];
    unpk4(reinterpret_cast<const uint2*>(xo)[(long)row * 256 + d], xr);
    float4 w1v = reinterpret_cast<const float4*>(w1)[d];
    float4 w2v = reinterpret_cast<const float4*>(w2)[d];
    float s1 = xr[0]*w1v.x + xr[1]*w1v.y + xr[2]*w1v.z + xr[3]*w1v.w;
    float s2 = xr[0]*w2v.x + xr[1]*w2v.y + xr[2]*w2v.z + xr[3]*w2v.w;
    #pragma unroll
    for (int o = 32; o > 0; o >>= 1) { s1 += __shfl_down(s1, o); s2 += __shfl_down(s2, o); }
    if (lane == 0) { sg1[wave] = s1; sg2[wave] = s2; }
    #pragma unroll
    for (int k = 0; k < 8; k++) {
        float v = qv * bf2f(keys[k * 256 + d]);
        #pragma unroll
        for (int o = 32; o > 0; o >>= 1) v += __shfl_down(v, o);
        if (lane == 0) sred[k][wave] = v;
    }
    __syncthreads();
    if (d < 8) sa[d] = (sred[d][0] + sred[d][1] + sred[d][2] + sred[d][3]) * 0.0625f;
    if (d == 0) {
        g1sh = 1.f / (1.f + __expf(-(sg1[0] + sg1[1] + sg1[2] + sg1[3])));
        gateb2[row] = 1.f / (1.f + __expf(-(sg2[0] + sg2[1] + sg2[2] + sg2[3])));
    }
    __syncthreads();
    if (d < 8) {
        float m = sa[0];
        #pragma unroll
        for (int k = 1; k < 8; k++) m = fmaxf(m, sa[k]);
        float e = __expf(sa[d] - m), sum = 0.f;
        #pragma unroll
        for (int k = 0; k < 8; k++) sum += __expf(sa[k] - m);
        wD[(long)row * 8 + d] = g1sh * e / sum;
    }
}

// partial avg + per-chunk weight sums
__global__ __launch_bounds__(256) void wm_avg_partial_k(
    const float* __restrict__ wD, const u16* __restrict__ cw,
    float* __restrict__ part, float* __restrict__ part2)
{
    int blk = blockIdx.x;
    int b = blk >> 6, k = (blk >> 3) & 7, ch = blk & 7;
    int d = threadIdx.x;
    const float* wp = wD + ((long)b * 2048 + ch * 256) * 8 + k;
    const u16*   cp = cw + ((long)b * 2048 + ch * 256) * 1024 + 256 + d;
    float acc = 0.f, wsum = 0.f;
    for (int s = 0; s < 256; s++) {
        float wv = wp[s * 8];
        acc += wv * bf2f(cp[(long)s * 1024]);
        wsum += wv;
    }
    part[(long)blk * 256 + d] = acc;
    if (d == 0) part2[blk] = wsum;
}

__global__ __launch_bounds__(256) void wm_final_k(
    const float* __restrict__ part, const float* __restrict__ part2,
    const float* __restrict__ wm, float* __restrict__ out)
{
    int bk = blockIdx.x;
    int d = threadIdx.x;
    float acc = 0.f, t = 0.f;
    #pragma unroll
    for (int ch = 0; ch < 8; ch++) {
        acc += part[((long)bk * 8 + ch) * 256 + d];
        t   += part2[bk * 8 + ch];
    }
    float alpha = fminf(fmaxf(t, 0.f), 1.f);
    float avg = acc / (t + 1e-6f);
    long base = (long)(bk >> 3) * 2056 + (bk & 7) * 257;
    out[base + d] = (1.f - alpha) * wm[base + d] + alpha * avg;
    if (d == 0) out[base + 256] = fminf(fmaxf(wm[base + 256] + t, 0.f), 1.f);
}

__global__ void colsum_wl_k(const u16* __restrict__ wl, float* __restrict__ totl)
{
    int b = blockIdx.z;
    int n = blockIdx.x * 256 + threadIdx.x;
    int s0 = blockIdx.y * 256;
    const u16* p = wl + ((long)b * 2048 + s0) * 768 + n;
    float acc = 0.f;
    for (int s = 0; s < 256; s++) acc += bf2f(p[(long)s * 768]);
    atomicAdd(&totl[b * 768 + n], acc);
}

// cache blend with fused 4-way split-K combine of bf16 partials
__global__ __launch_bounds__(256) void cache_blend_k(
    const float* __restrict__ cache, const u16* __restrict__ Pp, long pStride,
    const float* __restrict__ totl, float* __restrict__ out)
{
    int i4 = blockIdx.x * 256 + threadIdx.x;   // < 196608
    float s[4] = {0.f, 0.f, 0.f, 0.f};
    #pragma unroll
    for (int k = 0; k < 4; k++) {
        uint2 r = reinterpret_cast<const uint2*>(Pp + (long)k * pStride)[i4];
        float v[4]; unpk4(r, v);
        s[0] += v[0]; s[1] += v[1]; s[2] += v[2]; s[3] += v[3];
    }
    long i = (long)i4 * 4;
    int bn = (int)(i >> 8);
    float t = totl[bn];
    float a = fminf(fmaxf(t, 0.f), 1.f);
    float inv = a / (t + 1e-6f);
    float4 cv = reinterpret_cast<const float4*>(cache)[i4];
    float4 o;
    o.x = (1.f - a) * cv.x + s[0] * inv;
    o.y = (1.f - a) * cv.y + s[1] * inv;
    o.z = (1.f - a) * cv.z + s[2] * inv;
    o.w = (1.f - a) * cv.w + s[3] * inv;
    reinterpret_cast<float4*>(out)[i4] = o;
}

// ---------------------------------------------------------------------------
extern "C" void kernel_launch(void* const* d_in, const int* in_sizes, int n_in,
                              void* d_out, int out_size, void* d_ws, size_t ws_size,
                              hipStream_t stream)
{
    const int D = 1024, DC = 256, NL = 768;
    const long MS = 8192;
    const long SB = 2048;

    const float* x       = (const float*)d_in[0];
    const float* cache   = (const float*)d_in[1];
    const float* wm      = (const float*)d_in[2];
    const float* Wq_ltm  = (const float*)d_in[3];
    const float* Wo_ltm  = (const float*)d_in[4];
    const float* wg_ltm  = (const float*)d_in[5];
    const float* Wq_wm   = (const float*)d_in[6];
    const float* Wo_wm   = (const float*)d_in[7];
    const float* wg_wm   = (const float*)d_in[8];
    const float* conv1_w = (const float*)d_in[9];
    const float* conv1_b = (const float*)d_in[10];
    const float* conv2_w = (const float*)d_in[11];
    const float* conv2_b = (const float*)d_in[12];
    const float* ln_g    = (const float*)d_in[13];
    const float* ln_b    = (const float*)d_in[14];
    const float* Wqw_wm  = (const float*)d_in[15];
    const float* Ww_wm   = (const float*)d_in[16];
    const float* wm_keys = (const float*)d_in[17];
    const float* wgw_wm  = (const float*)d_in[18];
    const float* Wqw_ltm = (const float*)d_in[19];
    const float* Ww_ltm  = (const float*)d_in[20];
    const float* wgw_ltm = (const float*)d_in[21];

    float* out_f     = (float*)d_out;
    float* cache_out = out_f + 8388608;
    float* wm_out    = out_f + 8388608 + 786432;

    char* ws = (char*)d_ws;
    size_t off = 0;
    auto alloc = [&](size_t bytes) -> char* {
        char* p = ws + off;
        off = (off + bytes + 255) & ~(size_t)255;
        return p;
    };
    u16* Wqb     = (u16*)alloc((size_t)D*DC*2);
    u16* WoLt    = (u16*)alloc((size_t)D*DC*2);
    u16* WbigT   = (u16*)alloc((size_t)D*D*2);
    u16* c1wt    = (u16*)alloc((size_t)5*D*D*2);
    u16* c2wt    = (u16*)alloc((size_t)5*D*D*2);
    u16* cache_b = (u16*)alloc((size_t)4*NL*DC*2);
    u16* cache_t = (u16*)alloc((size_t)4*NL*DC*2);
    u16* keys_b  = (u16*)alloc((size_t)8*DC*2);
    u16* WqC     = (u16*)alloc((size_t)4*NL*D*2);
    u16* act0    = (u16*)alloc((size_t)MS*D*2);
    u16* act1    = (u16*)alloc((size_t)MS*D*2);
    u16* xltm    = (u16*)alloc((size_t)MS*D*2);
    u16* xpad1   = (u16*)alloc((size_t)4*2056*1024*2);
    u16* xpad2   = (u16*)alloc((size_t)4*2056*1024*2);
    u16* attnb   = (u16*)alloc((size_t)MS*NL*2);
    u16* readb   = (u16*)alloc((size_t)MS*DC*2);
    u16* Pu      = (u16*)alloc((size_t)16777216*2);
    float* CW    = (float*)alloc((size_t)4*8*D*4);
    float* WC    = (float*)alloc((size_t)4*8*D*4);
    float* gateb = (float*)alloc((size_t)MS*4);
    float* gateb2= (float*)alloc((size_t)MS*4);
    float* wD    = (float*)alloc((size_t)MS*8*4);
    float* totl  = (float*)alloc((size_t)4*NL*4);
    float* part  = (float*)alloc((size_t)256*256*4);
    float* part2 = (float*)alloc((size_t)256*4);
    u16*   qbig   = act0;    // cols: 0 qw | 256 cw | 512 ql | 768 cl

    // ---- mega-prep ----
    prep_k<<<21634, 256, 0, stream>>>(
        x, cache, wm_keys, wm, Wo_wm, Wq_wm,
        Wq_ltm, Wqw_wm, Ww_wm, Wqw_ltm, Ww_ltm, Wo_ltm, conv1_w, conv2_w,
        xpad1, xpad2, totl, act0, cache_b, keys_b,
        Wqb, WbigT, WoLt, c1wt, c2wt, cache_t, CW, WC);

    // ---- Phase A: LTM read ----
    // WqC = cache_b @ Wq_ltm^T, split-K=2 -> bf16 partials, ksum combine
    gemm_bf16<0,1,0,128,2,0><<<dim3(6,8,8), 256, 0, stream>>>(
        cache_b, Wqb, nullptr, nullptr, nullptr, nullptr,
        768,1024,256, 256,256, 196608L, 0L, 786432L, Pu, 3145728L, 0);
    ksum_k<2,1><<<3072, 256, 0, stream>>>(Pu, 3145728L, nullptr, WqC, 786432);
    gemv_sigmoid_k<<<2048, 256, 0, stream>>>(act0, wg_ltm, gateb);
    gemm_bf16<0,1,0,128,2,1><<<dim3(96,1,8), 256, 0, stream>>>(
        act0, WqC, nullptr, nullptr, nullptr, nullptr,
        2048,768,1024, 1024,1024, SB*1024, 786432L, SB*768, Pu, 6291456L, 6);
    softmax768_k<2><<<8192, 256, 0, stream>>>(Pu, 6291456L, attnb, nullptr);
    gemm_bf16<0,1,0,64,4,1><<<dim3(64,1,16), 256, 0, stream>>>(
        attnb, cache_t, nullptr, nullptr, nullptr, nullptr,
        2048,256,768, 768,768, SB*768, (long)NL*DC, SB*256, Pu, 2097152L, 4);
    ksum_k<4,1><<<2048, 256, 0, stream>>>(Pu, 2097152L, nullptr, readb, 524288);
    gemm_bf16<0,1,6,128,1,1><<<dim3(512,1,1), 256, 0, stream>>>(
        readb, WoLt, nullptr, xltm, (const float*)act0, gateb,
        8192,1024,256, 256,256, 0,0,0, nullptr, 0, 8);

    // ---- Phase B: WM read (bf16 x_ltm, writes padded xpad1 only) ----
    wm_read_fused_k<<<8192, 256, 0, stream>>>(WC, CW, wg_wm, xltm, xpad1);

    // ---- Phase C: convs (interleaved counted-vmcnt, split-K=2) + gelu+LN ----
    conv8_k<1><<<dim3(32,4,2), 512, 0, stream>>>(xpad1, c1wt, Pu, Pu + 8388608);
    gelu_reduce_k<<<8192, 256, 0, stream>>>(Pu, Pu + 8388608, xpad1, conv1_b, xpad2);
    conv8_k<2><<<dim3(32,4,2), 512, 0, stream>>>(xpad2, c2wt, Pu, Pu + 8388608);
    gelu_ln_k<<<8192, 256, 0, stream>>>(
        Pu, Pu + 8388608, xpad2, conv2_b, ln_g, ln_b, out_f, act1);

    // ---- Phase D: all four write-projections in one GEMM (swizzled) ----
    gemm_bf16<0,1,0,128,1,1><<<dim3(512,1,1), 256, 0, stream>>>(
        act1, WbigT, nullptr, qbig, nullptr, nullptr,
        8192,1024,1024, 1024,1024, 0,0,0, nullptr, 0, 8);
    attn8_wg_k<<<8192, 256, 0, stream>>>(qbig, act1, wgw_wm, wgw_ltm, keys_b, wD, gateb2);
    wm_avg_partial_k<<<256, 256, 0, stream>>>(wD, qbig, part, part2);
    wm_final_k<<<32, 256, 0, stream>>>(part, part2, wm, wm_out);

    // ---- Phase E: LTM write ----
    gemm_bf16<0,1,0,128,2,1><<<dim3(96,1,8), 256, 0, stream>>>(
        qbig + 512, cache_b, nullptr, nullptr, nullptr, nullptr,
        2048,768,256, 1024,256, SB*1024, (long)NL*DC, SB*768, Pu, 6291456L, 6);
    softmax768_k<2><<<8192, 256, 0, stream>>>(Pu, 6291456L, attnb, gateb2);
    colsum_wl_k<<<dim3(3, 8, 4), 256, 0, stream>>>(attnb, totl);
    gemm_bf16<1,0,1,64,4,0><<<dim3(6,4,16), 256, 0, stream>>>(
        attnb, qbig + 768, nullptr, nullptr, nullptr, nullptr,
        768,256,2048, 768,1024, SB*768, SB*1024, 196608L, Pu, 786432L, 0);
    cache_blend_k<<<768, 256, 0, stream>>>(cache, Pu, 786432L, totl, cache_out);

    (void)in_sizes; (void)n_in; (void)out_size; (void)ws_size;
}

// Round 16
// 474.595 us; speedup vs baseline: 1.0185x; 1.0185x over previous
//
#include <hip/hip_runtime.h>
#include <stdint.h>

typedef unsigned short u16;
typedef unsigned int u32;
typedef __attribute__((ext_vector_type(8))) short s16x8;
typedef __attribute__((ext_vector_type(4))) float f32x4;

__device__ __forceinline__ float bf2f(u16 u) {
    return __builtin_bit_cast(float, (u32)u << 16);
}
__device__ __forceinline__ u16 f2bf(float f) {
    u32 u = __builtin_bit_cast(u32, f);
    u += 0x7FFFu + ((u >> 16) & 1u);
    return (u16)(u >> 16);
}
__device__ __forceinline__ void unpk4(uint2 r, float* o) {
    o[0] = bf2f((u16)(r.x & 0xffff)); o[1] = bf2f((u16)(r.x >> 16));
    o[2] = bf2f((u16)(r.y & 0xffff)); o[3] = bf2f((u16)(r.y >> 16));
}

// async global->LDS, 16 bytes per lane. LDS dest must be linear in lane order.
__device__ __forceinline__ void gl16(const u16* g, u16* l) {
    __builtin_amdgcn_global_load_lds(
        (const __attribute__((address_space(1))) u32*)(const void*)g,
        (__attribute__((address_space(3))) u32*)(void*)l, 16, 0, 0);
}

#define BAR() { __builtin_amdgcn_sched_barrier(0); __builtin_amdgcn_s_barrier(); __builtin_amdgcn_sched_barrier(0); }

// ---------------------------------------------------------------------------
// 256x256 conv GEMM — interleaved counted-vmcnt schedule (R13, 85.6us).
// ---------------------------------------------------------------------------
template<int DIL>
__global__ __launch_bounds__(512) void conv8_k(
    const u16* __restrict__ Apad, const u16* __restrict__ Bw,
    u16* __restrict__ Cb0, u16* __restrict__ Cb1)
{
    __shared__ u16 sA[2][16384];
    __shared__ u16 sB[2][16384];
    const int tid  = threadIdx.x;
    const int wid  = tid >> 6;
    const int lane = tid & 63;
    const int wr = (wid >> 2) * 128;
    const int wc = (wid & 3) * 64;
    const int lr = lane & 15;
    const int kq = lane >> 4;
    const int batch = blockIdx.x >> 3;
    const int m0b   = (blockIdx.x & 7) * 256;
    const int bn0   = blockIdx.y * 256;
    const int kbeg  = blockIdx.z * 2560;
    const u16* Ab = Apad + (long)batch * 2056 * 1024;

    const int row0 = tid >> 3;
    const int g0   = (tid & 7) ^ (row0 & 7);

    f32x4 acc[8][4] = {};
    s16x8 aF[4][2], bF[4][2];

    auto stageA2 = [&](int nb, int kt, int c) {
        const int ktabs = kbeg + kt * 64;
        const int tap = ktabs >> 10;
        const long rbase = (long)(8 + m0b + c * 64 + (tap - 4) * DIL) * 1024
                           + (ktabs & 1023) + g0 * 8;
        u16* dst = &sA[nb][(c * 64) * 64 + tid * 8];
        gl16(Ab + rbase + (long)row0 * 1024, dst);
        gl16(Ab + rbase + (long)(row0 + 128) * 1024, dst + 8192);
    };
    auto stageB = [&](int nb, int kt, int h) {
        const int ktabs = kbeg + kt * 64;
        const long rbase = (long)(bn0 + h * 128) * 5120 + ktabs + g0 * 8;
        u16* dst = &sB[nb][h * 8192 + tid * 8];
        gl16(Bw + rbase + (long)row0 * 5120, dst);
        gl16(Bw + rbase + (long)(row0 + 64) * 5120, dst + 4096);
    };
    auto readA = [&](int nb, int mq) {
        #pragma unroll
        for (int m = 0; m < 4; m++) {
            const int row = wr + (mq * 4 + m) * 16 + lr;
            #pragma unroll
            for (int ks = 0; ks < 2; ks++) {
                const int chunk = ks * 4 + kq;
                aF[m][ks] = *(const s16x8*)&sA[nb][row * 64 + ((chunk ^ (row & 7)) << 3)];
            }
        }
    };
    auto readB4 = [&](int nb, int nq) {
        #pragma unroll
        for (int n = 0; n < 2; n++) {
            const int row = wc + (nq * 2 + n) * 16 + lr;
            #pragma unroll
            for (int ks = 0; ks < 2; ks++) {
                const int chunk = ks * 4 + kq;
                bF[nq * 2 + n][ks] = *(const s16x8*)&sB[nb][row * 64 + ((chunk ^ (row & 7)) << 3)];
            }
        }
    };

#define MFQ(MQ, NQ) \
    { __builtin_amdgcn_s_setprio(1); \
      _Pragma("unroll") \
      for (int m = 0; m < 4; m++) { \
        _Pragma("unroll") \
        for (int n = 0; n < 2; n++) { \
          _Pragma("unroll") \
          for (int ks = 0; ks < 2; ks++) \
            acc[(MQ)*4+m][(NQ)*2+n] = __builtin_amdgcn_mfma_f32_16x16x32_bf16( \
                aF[m][ks], bF[(NQ)*2+n][ks], acc[(MQ)*4+m][(NQ)*2+n], 0, 0, 0); \
        } } \
      __builtin_amdgcn_s_setprio(0); }

    stageB(0, 0, 0); stageB(0, 0, 1); stageA2(0, 0, 0); stageA2(0, 0, 1);

    const int NT = 40;
    for (int t = 0; t < NT; ++t) {
        const int nb = t & 1;
        asm volatile("s_waitcnt vmcnt(2)" ::: "memory");
        BAR();
        readB4(nb, 0); readB4(nb, 1); readA(nb, 0);
        if (t + 1 < NT) stageB(nb ^ 1, t + 1, 0);
        MFQ(0, 0);
        if (t + 1 < NT) stageB(nb ^ 1, t + 1, 1);
        MFQ(0, 1);
        if (t + 1 < NT) { asm volatile("s_waitcnt vmcnt(4)" ::: "memory"); }
        else            { asm volatile("s_waitcnt vmcnt(0)" ::: "memory"); }
        BAR();
        readA(nb, 1);
        if (t + 1 < NT) stageA2(nb ^ 1, t + 1, 0);
        MFQ(1, 0);
        if (t + 1 < NT) stageA2(nb ^ 1, t + 1, 1);
        MFQ(1, 1);
    }
#undef MFQ

    u16* C = (blockIdx.z ? Cb1 : Cb0) + (long)batch * 2048 * 1024;
    #pragma unroll
    for (int m = 0; m < 8; m++) {
        #pragma unroll
        for (int n = 0; n < 4; n++) {
            const int cc = bn0 + wc + n * 16 + lr;
            #pragma unroll
            for (int j = 0; j < 4; j++) {
                const int r = m0b + wr + m * 16 + kq * 4 + j;
                C[(long)r * 1024 + cc] = f2bf(acc[m][n][j]);
            }
        }
    }
}

// ---------------------------------------------------------------------------
// bf16 MFMA GEMM (m97 staging). Tile 128 x TN, BK=32, 4 waves, 16x16x32 MFMA.
// EPI: 0 bf16 C; 1 f32 C; 2 gated residual (f32+bf16); 5 gated res (f32 only);
//      6 gated residual, bf16 res in (res reinterpreted as u16*) + bf16 out
// KS>1: bf16 partials to Pp (elems; slice stride pStride).
// ---------------------------------------------------------------------------
template<int AL, int BL, int EPI, int TN, int KS, int SWZ>
__global__ __launch_bounds__(256) void gemm_bf16(
    const u16* __restrict__ A, const u16* __restrict__ B,
    float* __restrict__ Cf, u16* __restrict__ Cb,
    const float* __restrict__ res, const float* __restrict__ gate,
    int M, int N, int K, int lda, int ldb,
    long aBS, long bBS, long cBS,
    u16* __restrict__ Pp, long pStride, int nby)
{
    constexpr int NFRAG = TN / 32;
    __shared__ u16 sA[128 * 32];
    __shared__ u16 sB[TN * 32];
    const int tid  = threadIdx.x;
    const int lane = tid & 63;
    const int wave = tid >> 6;
    const int wr = (wave >> 1) * 64;
    const int wc = (wave & 1) * (TN / 2);

    int bidx, bidy;
    if (SWZ) {
        const int nb  = gridDim.x;
        const int cpx = nb >> 3;
        const int bf  = blockIdx.x;
        const int sw  = (bf & 7) * cpx + (bf >> 3);
        bidx = sw / nby; bidy = sw - bidx * nby;
    } else {
        bidx = blockIdx.x; bidy = blockIdx.y;
    }
    const int m0 = bidx * 128;
    const int n0 = bidy * TN;
    const int zz = blockIdx.z;
    const long bz = (KS > 1) ? (zz / KS) : zz;
    const int ks  = (KS > 1) ? (zz % KS) : 0;
    const u16* Ab = A + bz * aBS;
    const u16* Bb = B + bz * bBS;

    f32x4 acc[4][NFRAG] = {};
    const int lr = lane & 15;
    const int lk = (lane >> 4) << 3;
    const int ar0 = tid >> 2;
    const int akg = (tid & 3) << 3;

    const int Kp = K / KS;
    const int kbeg = ks * Kp, kend = kbeg + Kp;

    for (int kk = kbeg; kk < kend; kk += 32) {
        __syncthreads();
        if (AL == 0) {
            gl16(Ab + (long)(m0 + ar0) * lda + kk + akg,      sA + tid * 8);
            gl16(Ab + (long)(m0 + ar0 + 64) * lda + kk + akg, sA + tid * 8 + 2048);
        } else {     // AL==1: A^T source, strided gather
            for (int t = tid; t < 512; t += 256) {
                int row = t & 127, kg = (t >> 7) << 3;
                u32 w0[4];
                #pragma unroll
                for (int j2 = 0; j2 < 4; j2++) {
                    u16 lo = Ab[(long)(kk + kg + 2*j2    ) * lda + m0 + row];
                    u16 hi = Ab[(long)(kk + kg + 2*j2 + 1) * lda + m0 + row];
                    w0[j2] = (u32)lo | ((u32)hi << 16);
                }
                uint4 v; v.x = w0[0]; v.y = w0[1]; v.z = w0[2]; v.w = w0[3];
                *reinterpret_cast<uint4*>(sA + row * 32 + kg) = v;
            }
        }
        if (BL == 1) {
            gl16(Bb + (long)(n0 + ar0) * ldb + kk + akg, sB + tid * 8);
            if (TN == 128)
                gl16(Bb + (long)(n0 + ar0 + 64) * ldb + kk + akg, sB + tid * 8 + 2048);
        } else {
            for (int t = tid; t < TN * 4; t += 256) {
                int col = t & (TN - 1), kg = (t / TN) << 3;
                u32 w0[4];
                #pragma unroll
                for (int j2 = 0; j2 < 4; j2++) {
                    u16 lo = Bb[(long)(kk + kg + 2*j2    ) * ldb + n0 + col];
                    u16 hi = Bb[(long)(kk + kg + 2*j2 + 1) * ldb + n0 + col];
                    w0[j2] = (u32)lo | ((u32)hi << 16);
                }
                uint4 v; v.x = w0[0]; v.y = w0[1]; v.z = w0[2]; v.w = w0[3];
                *reinterpret_cast<uint4*>(sB + col * 32 + kg) = v;
            }
        }
        __syncthreads();
        s16x8 aF[4], bF[NFRAG];
        #pragma unroll
        for (int m = 0; m < 4; m++)
            aF[m] = *reinterpret_cast<const s16x8*>(sA + (wr + m*16 + lr) * 32 + lk);
        #pragma unroll
        for (int n = 0; n < NFRAG; n++)
            bF[n] = *reinterpret_cast<const s16x8*>(sB + (wc + n*16 + lr) * 32 + lk);
        #pragma unroll
        for (int m = 0; m < 4; m++)
            #pragma unroll
            for (int n = 0; n < NFRAG; n++)
                acc[m][n] = __builtin_amdgcn_mfma_f32_16x16x32_bf16(aF[m], bF[n], acc[m][n], 0, 0, 0);
    }

    const int rj = (lane >> 4) << 2;
    if (KS > 1) {
        u16* Pb = Pp + (long)ks * pStride + bz * cBS;
        #pragma unroll
        for (int m = 0; m < 4; m++)
            #pragma unroll
            for (int n = 0; n < NFRAG; n++) {
                const int cc = n0 + wc + n*16 + lr;
                #pragma unroll
                for (int j = 0; j < 4; j++) {
                    const int r = m0 + wr + m*16 + rj + j;
                    Pb[(long)r * N + cc] = f2bf(acc[m][n][j]);
                }
            }
        return;
    }

    float* Cfb = Cf + bz * cBS;
    #pragma unroll
    for (int m = 0; m < 4; m++) {
        #pragma unroll
        for (int n = 0; n < NFRAG; n++) {
            const int cc = n0 + wc + n*16 + lr;
            #pragma unroll
            for (int j = 0; j < 4; j++) {
                const int r = m0 + wr + m*16 + rj + j;
                const long idx = (long)r * N + cc;
                const float v = acc[m][n][j];
                if (EPI == 0) {
                    Cb[bz * cBS + idx] = f2bf(v);
                } else if (EPI == 1) {
                    Cfb[idx] = v;
                } else if (EPI == 6) {
                    float o = bf2f(reinterpret_cast<const u16*>(res)[idx]) + gate[r] * v;
                    Cb[idx] = f2bf(o);
                } else {   // 2 or 5: gated residual, f32 res
                    float o = res[idx] + gate[r] * v;
                    Cfb[idx] = o;
                    if (EPI == 2) Cb[idx] = f2bf(o);
                }
            }
        }
    }
}

// split-K combine over bf16 partials; BF=1 -> bf16 out, else f32 out
template<int KS, int BF>
__global__ __launch_bounds__(256) void ksum_k(
    const u16* __restrict__ Pp, long pStride,
    float* __restrict__ outf, u16* __restrict__ outb, int n4)
{
    int i = blockIdx.x * 256 + threadIdx.x;
    if (i >= n4) return;
    float s[4] = {0.f, 0.f, 0.f, 0.f};
    #pragma unroll
    for (int k = 0; k < KS; k++) {
        uint2 r = reinterpret_cast<const uint2*>(Pp + (long)k * pStride)[i];
        float v[4]; unpk4(r, v);
        s[0] += v[0]; s[1] += v[1]; s[2] += v[2]; s[3] += v[3];
    }
    if (BF) {
        u32 lo = (u32)f2bf(s[0]) | ((u32)f2bf(s[1]) << 16);
        u32 hi = (u32)f2bf(s[2]) | ((u32)f2bf(s[3]) << 16);
        reinterpret_cast<uint2*>(outb)[i] = make_uint2(lo, hi);
    } else {
        float4 o; o.x = s[0]; o.y = s[1]; o.z = s[2]; o.w = s[3];
        reinterpret_cast<float4*>(outf)[i] = o;
    }
}

// ---------------------------------------------------------------------------
// Mega-prep: zero-init, converts (incl. Wq_ltm bf16), transposes, CW, WC.
// ---------------------------------------------------------------------------
__global__ __launch_bounds__(256) void prep_k(
    const float* __restrict__ x, const float* __restrict__ cache,
    const float* __restrict__ wm_keys, const float* __restrict__ wm,
    const float* __restrict__ Wo_wm, const float* __restrict__ Wq_wm,
    const float* __restrict__ Wq_ltm, const float* __restrict__ Wqw_wm,
    const float* __restrict__ Ww_wm, const float* __restrict__ Wqw_ltm,
    const float* __restrict__ Ww_ltm, const float* __restrict__ Wo_ltm,
    const float* __restrict__ conv1_w, const float* __restrict__ conv2_w,
    u16* __restrict__ xpad1, u16* __restrict__ xpad2,
    float* __restrict__ totl,
    u16* __restrict__ act0, u16* __restrict__ cache_b, u16* __restrict__ keys_b,
    u16* __restrict__ Wqb, u16* __restrict__ WbigT,
    u16* __restrict__ WoLt, u16* __restrict__ c1wt, u16* __restrict__ c2wt,
    u16* __restrict__ cache_t, float* __restrict__ CW, float* __restrict__ WC)
{
    __shared__ float tile[32][33];
    int b = blockIdx.x;
    int tid = threadIdx.x;

    if (b < 64) {
        int i = b * 256 + tid;
        int bt = i >> 12, j = i & 4095;
        long offp = (long)bt * (2056L * 1024 / 2) + j;
        reinterpret_cast<u32*>(xpad1)[offp] = 0u;
        reinterpret_cast<u32*>(xpad2)[offp] = 0u;
        if (i < 3072) totl[i] = 0.f;
        return;
    }
    b -= 64;
    if (b < 9218) {
        const float* in; u16* out; int i;
        if (b < 8192)      { in = x;       out = act0;    i = b * 256 + tid; }
        else if (b < 8960) { in = cache;   out = cache_b; i = (b - 8192) * 256 + tid; }
        else if (b < 8962) { in = wm_keys; out = keys_b;  i = (b - 8960) * 256 + tid; }
        else               { in = Wq_ltm;  out = Wqb;     i = (b - 8962) * 256 + tid; }
        float4 v = reinterpret_cast<const float4*>(in)[i];
        u32 lo = (u32)f2bf(v.x) | ((u32)f2bf(v.y) << 16);
        u32 hi = (u32)f2bf(v.z) | ((u32)f2bf(v.w) << 16);
        reinterpret_cast<uint2*>(out)[i] = make_uint2(lo, hi);
        return;
    }
    b -= 9218;
    if (b < 12288) {
        const float* in; u16* out; int R, C, l;
        if (b < 1024) {
            l = b & 255; R = 1024; C = 256;
            int m = b >> 8;
            if      (m == 0) { in = Wqw_wm;  out = WbigT; }
            else if (m == 1) { in = Ww_wm;   out = WbigT + 262144; }
            else if (m == 2) { in = Wqw_ltm; out = WbigT + 524288; }
            else             { in = Ww_ltm;  out = WbigT + 786432; }
        } else if (b < 1280) {
            l = b - 1024; in = Wo_ltm; out = WoLt; R = 256; C = 1024;
        } else if (b < 6400) {
            l = b - 1280; in = conv1_w; out = c1wt; R = 5120; C = 1024;
        } else if (b < 11520) {
            l = b - 6400; in = conv2_w; out = c2wt; R = 5120; C = 1024;
        } else {
            int lb = b - 11520;
            int z = lb / 192; l = lb % 192;
            in = cache + (long)z * 196608; out = cache_t + (long)z * 196608;
            R = 768; C = 256;
        }
        const int ct = C >> 5;
        const int c0 = (l % ct) * 32, r0 = (l / ct) * 32;
        int tx = tid & 31, ty = tid >> 5;
        #pragma unroll
        for (int i = 0; i < 32; i += 8)
            tile[ty + i][tx] = in[(long)(r0 + ty + i) * C + c0 + tx];
        __syncthreads();
        #pragma unroll
        for (int i = 0; i < 32; i += 8)
            out[(long)(c0 + ty + i) * R + r0 + tx] = f2bf(tile[tx][ty + i]);
        return;
    }
    b -= 12288;
    if (b < 32) {
        const float* wrow = wm + (long)(b >> 3) * 2056 + (b & 7) * 257;
        int c = tid;
        float a0 = 0.f, a1 = 0.f, a2 = 0.f, a3 = 0.f;
        for (int dd = 0; dd < 256; dd++) {
            float w = wrow[dd];
            const float* wo = Wo_wm + (long)dd * 1024;
            a0 += w * wo[c]; a1 += w * wo[c + 256];
            a2 += w * wo[c + 512]; a3 += w * wo[c + 768];
        }
        float* o = CW + (long)b * 1024;
        o[c] = a0; o[c + 256] = a1; o[c + 512] = a2; o[c + 768] = a3;
        return;
    }
    b -= 32;
    {
        const float* wrow = wm + (long)(b >> 3) * 2056 + (b & 7) * 257;
        int c = tid;
        float a0 = 0.f, a1 = 0.f, a2 = 0.f, a3 = 0.f;
        for (int j = 0; j < 256; j++) {
            float w = wrow[j];
            a0 += Wq_wm[(long)(c      ) * 256 + j] * w;
            a1 += Wq_wm[(long)(c + 256) * 256 + j] * w;
            a2 += Wq_wm[(long)(c + 512) * 256 + j] * w;
            a3 += Wq_wm[(long)(c + 768) * 256 + j] * w;
        }
        float* o = WC + (long)b * 1024;
        o[c] = a0; o[c + 256] = a1; o[c + 512] = a2; o[c + 768] = a3;
    }
}

// gate = sigmoid(bf16_row . w)
__global__ __launch_bounds__(256) void gemv_sigmoid_k(
    const u16* __restrict__ X, const float* __restrict__ w,
    float* __restrict__ out)
{
    int row  = blockIdx.x * 4 + (threadIdx.x >> 6);
    int lane = threadIdx.x & 63;
    const u16* xr = X + (long)row * 1024;
    float s = 0.f;
    for (int i = lane * 4; i < 1024; i += 256) {
        uint2 r = *reinterpret_cast<const uint2*>(xr + i);
        float v[4]; unpk4(r, v);
        s += v[0]*w[i] + v[1]*w[i+1] + v[2]*w[i+2] + v[3]*w[i+3];
    }
    #pragma unroll
    for (int o = 32; o > 0; o >>= 1) s += __shfl_down(s, o);
    if (lane == 0) out[row] = 1.f / (1.f + __expf(-s));
}

// softmax over 768 bf16 scores (scale 1/16), summing KS bf16 partial slices
template<int KS>
__global__ __launch_bounds__(256) void softmax768_k(
    const u16* __restrict__ scores, long pStride, u16* __restrict__ out,
    const float* __restrict__ gate)
{
    __shared__ float s4[4], s4b[4];
    int row = blockIdx.x;
    int t = threadIdx.x;
    const u16* sr = scores + (long)row * 768;
    float v[3];
    float m = -1e30f;
    #pragma unroll
    for (int i = 0; i < 3; i++) {
        float sv = bf2f(sr[t + i*256]);
        #pragma unroll
        for (int k = 1; k < KS; k++) sv += bf2f(sr[(long)k * pStride + t + i*256]);
        v[i] = sv * 0.0625f; m = fmaxf(m, v[i]);
    }
    float wm_ = m;
    #pragma unroll
    for (int o = 32; o > 0; o >>= 1) wm_ = fmaxf(wm_, __shfl_down(wm_, o));
    if ((t & 63) == 0) s4[t >> 6] = wm_;
    __syncthreads();
    float bm = fmaxf(fmaxf(s4[0], s4[1]), fmaxf(s4[2], s4[3]));
    float sum = 0.f;
    #pragma unroll
    for (int i = 0; i < 3; i++) { v[i] = __expf(v[i] - bm); sum += v[i]; }
    #pragma unroll
    for (int o = 32; o > 0; o >>= 1) sum += __shfl_down(sum, o);
    if ((t & 63) == 0) s4b[t >> 6] = sum;
    __syncthreads();
    float bs = s4b[0] + s4b[1] + s4b[2] + s4b[3];
    float g = gate ? gate[row] : 1.0f;
    float inv = g / bs;
    u16* orow = out + (long)row * 768;
    #pragma unroll
    for (int i = 0; i < 3; i++) orow[t + i*256] = f2bf(v[i] * inv);
}

// Fused WM-read v4: bf16 x_ltm in, gate dot folded, writes ONLY padded xpad1.
__global__ __launch_bounds__(256) void wm_read_fused_k(
    const float* __restrict__ WC, const float* __restrict__ CW,
    const float* __restrict__ wg, const u16* __restrict__ xltm,
    u16* __restrict__ outb)
{
    __shared__ float sred[8][4];
    __shared__ float sg4[4];
    __shared__ float sa[8];
    __shared__ float gsh;
    int row = blockIdx.x;
    int b = row >> 11;
    int d = threadIdx.x, lane = d & 63, wave = d >> 6;
    long orow = (long)row * 1024;
    float rv[4];
    rv[0] = bf2f(xltm[orow + d]);
    rv[1] = bf2f(xltm[orow + d + 256]);
    rv[2] = bf2f(xltm[orow + d + 512]);
    rv[3] = bf2f(xltm[orow + d + 768]);
    float gp = rv[0] * wg[d] + rv[1] * wg[d + 256] + rv[2] * wg[d + 512] + rv[3] * wg[d + 768];
    #pragma unroll
    for (int o = 32; o > 0; o >>= 1) gp += __shfl_down(gp, o);
    if (lane == 0) sg4[wave] = gp;
    const float* wcb = WC + (long)b * 8192;
    #pragma unroll
    for (int k = 0; k < 8; k++) {
        const float* w = wcb + k * 1024;
        float v = rv[0] * w[d] + rv[1] * w[d + 256] + rv[2] * w[d + 512] + rv[3] * w[d + 768];
        #pragma unroll
        for (int o = 32; o > 0; o >>= 1) v += __shfl_down(v, o);
        if (lane == 0) sred[k][wave] = v;
    }
    __syncthreads();
    if (d < 8) sa[d] = (sred[d][0] + sred[d][1] + sred[d][2] + sred[d][3]) * 0.0625f;
    if (d == 0) gsh = 1.f / (1.f + __expf(-(sg4[0] + sg4[1] + sg4[2] + sg4[3])));
    __syncthreads();
    float m = sa[0];
    #pragma unroll
    for (int k = 1; k < 8; k++) m = fmaxf(m, sa[k]);
    float e[8], sum = 0.f;
    #pragma unroll
    for (int k = 0; k < 8; k++) { e[k] = __expf(sa[k] - m); sum += e[k]; }
    float inv = 1.f / sum;
    #pragma unroll
    for (int k = 0; k < 8; k++) e[k] *= inv;
    float g = gsh;
    const float* cwb = CW + (long)b * 8192;
    long prow = ((long)(row >> 11) * 2056 + 8 + (row & 2047)) * 1024;
    #pragma unroll
    for (int j = 0; j < 4; j++) {
        int c = d + j * 256;
        float acc = 0.f;
        #pragma unroll
        for (int k = 0; k < 8; k++) acc += e[k] * cwb[k * 1024 + c];
        outb[prow + c] = f2bf(rv[j] + g * acc);
    }
}

// conv1 combine: bf16 partials + gelu + residual from padded bf16; writes padded bf16 only
__global__ __launch_bounds__(256) void gelu_reduce_k(
    const u16* __restrict__ p0, const u16* __restrict__ p1,
    const u16* __restrict__ resp, const float* __restrict__ bias,
    u16* __restrict__ outp)
{
    int i4 = blockIdx.x * 256 + threadIdx.x;
    int r = i4 >> 8, c4 = (i4 & 255) << 2;
    long prow = ((long)(r >> 11) * 2056 + 8 + (r & 2047)) * 1024 + c4;
    float a[4], b[4], rr[4];
    unpk4(reinterpret_cast<const uint2*>(p0)[i4], a);
    unpk4(reinterpret_cast<const uint2*>(p1)[i4], b);
    unpk4(*reinterpret_cast<const uint2*>(resp + prow), rr);
    float4 bi = *reinterpret_cast<const float4*>(bias + c4);
    const float C0 = 0.79788456080286535588f, C1 = 0.044715f;
    float y0 = a[0] + b[0] + bi.x, y1 = a[1] + b[1] + bi.y;
    float y2 = a[2] + b[2] + bi.z, y3 = a[3] + b[3] + bi.w;
    float o0 = rr[0] + 0.5f * y0 * (1.f + tanhf(C0 * (y0 + C1 * y0 * y0 * y0)));
    float o1 = rr[1] + 0.5f * y1 * (1.f + tanhf(C0 * (y1 + C1 * y1 * y1 * y1)));
    float o2 = rr[2] + 0.5f * y2 * (1.f + tanhf(C0 * (y2 + C1 * y2 * y2 * y2)));
    float o3 = rr[3] + 0.5f * y3 * (1.f + tanhf(C0 * (y3 + C1 * y3 * y3 * y3)));
    u32 lo = (u32)f2bf(o0) | ((u32)f2bf(o1) << 16);
    u32 hi = (u32)f2bf(o2) | ((u32)f2bf(o3) << 16);
    *reinterpret_cast<uint2*>(outp + prow) = make_uint2(lo, hi);
}

// conv2 combine + gelu residual (from padded bf16) + layernorm -> f32 out + bf16 act
__global__ __launch_bounds__(256) void gelu_ln_k(
    const u16* __restrict__ p0, const u16* __restrict__ p1,
    const u16* __restrict__ resp, const float* __restrict__ bias,
    const float* __restrict__ g, const float* __restrict__ b,
    float* __restrict__ outf, u16* __restrict__ outb)
{
    __shared__ float rs[4], rss[4];
    int row = blockIdx.x, t = threadIdx.x;
    long i4 = (long)row * 256 + t;
    long prow = ((long)(row >> 11) * 2056 + 8 + (row & 2047)) * 1024 + (t << 2);
    float a[4], pb[4], rr[4];
    unpk4(reinterpret_cast<const uint2*>(p0)[i4], a);
    unpk4(reinterpret_cast<const uint2*>(p1)[i4], pb);
    unpk4(*reinterpret_cast<const uint2*>(resp + prow), rr);
    float4 bi = reinterpret_cast<const float4*>(bias)[t];
    const float C0 = 0.79788456080286535588f, C1 = 0.044715f;
    float y0 = a[0] + pb[0] + bi.x, y1 = a[1] + pb[1] + bi.y;
    float y2 = a[2] + pb[2] + bi.z, y3 = a[3] + pb[3] + bi.w;
    float o0 = rr[0] + 0.5f * y0 * (1.f + tanhf(C0 * (y0 + C1 * y0 * y0 * y0)));
    float o1 = rr[1] + 0.5f * y1 * (1.f + tanhf(C0 * (y1 + C1 * y1 * y1 * y1)));
    float o2 = rr[2] + 0.5f * y2 * (1.f + tanhf(C0 * (y2 + C1 * y2 * y2 * y2)));
    float o3 = rr[3] + 0.5f * y3 * (1.f + tanhf(C0 * (y3 + C1 * y3 * y3 * y3)));
    float s  = o0 + o1 + o2 + o3;
    float ss = o0*o0 + o1*o1 + o2*o2 + o3*o3;
    #pragma unroll
    for (int o = 32; o > 0; o >>= 1) { s += __shfl_down(s, o); ss += __shfl_down(ss, o); }
    if ((t & 63) == 0) { rs[t >> 6] = s; rss[t >> 6] = ss; }
    __syncthreads();
    float S = rs[0]+rs[1]+rs[2]+rs[3];
    float SS = rss[0]+rss[1]+rss[2]+rss[3];
    float mean = S * (1.f/1024.f);
    float var  = SS * (1.f/1024.f) - mean*mean;
    float rstd = rsqrtf(var + 1e-5f);
    float4 gg = reinterpret_cast<const float4*>(g)[t];
    float4 bv = reinterpret_cast<const float4*>(b)[t];
    float4 y;
    y.x = (o0-mean)*rstd*gg.x + bv.x;
    y.y = (o1-mean)*rstd*gg.y + bv.y;
    y.z = (o2-mean)*rstd*gg.z + bv.z;
    y.w = (o3-mean)*rstd*gg.w + bv.w;
    reinterpret_cast<float4*>(outf)[i4] = y;
    u32 lo = (u32)f2bf(y.x) | ((u32)f2bf(y.y) << 16);
    u32 hi = (u32)f2bf(y.z) | ((u32)f2bf(y.w) << 16);
    reinterpret_cast<uint2*>(outb)[i4] = make_uint2(lo, hi);
}

// Fused: both write-gates (bf16 LN row) + WM key attention.
__global__ __launch_bounds__(256) void attn8_wg_k(
    const u16* __restrict__ q, const u16* __restrict__ xo,
    const float* __restrict__ w1, const float* __restrict__ w2,
    const u16* __restrict__ keys, float* __restrict__ wD,
    float* __restrict__ gateb2)
{
    __shared__ float sred[8][4];
    __shared__ float sa[8];
    __shared__ float sg1[4], sg2[4];
    __shared__ float g1sh;
    int row = blockIdx.x;
    int d = threadIdx.x, lane = d & 63, wave = d >> 6;
    float qv = bf2f(q[(long)row * 1024 + d]);
    float xr[4];
    unpk4(reinterpret_cast<const uint2*>(xo)[(long)row * 256 + d], xr);
    float4 w1v = reinterpret_cast<const float4*>(w1)[d];
    float4 w2v = reinterpret_cast<const float4*>(w2)[d];
    float s1 = xr[0]*w1v.x + xr[1]*w1v.y + xr[2]*w1v.z + xr[3]*w1v.w;
    float s2 = xr[0]*w2v.x + xr[1]*w2v.y + xr[2]*w2v.z + xr[3]*w2v.w;
    #pragma unroll
    for (int o = 32; o > 0; o >>= 1) { s1 += __shfl_down(s1, o); s2 += __shfl_down(s2, o); }
    if (lane == 0) { sg1[wave] = s1; sg2[wave] = s2; }
    #pragma unroll
    for (int k = 0; k < 8; k++) {
        float v = qv * bf2f(keys[k * 256 + d]);
        #pragma unroll
        for (int o = 32; o > 0; o >>= 1) v += __shfl_down(v, o);
        if (lane == 0) sred[k][wave] = v;
    }
    __syncthreads();
    if (d < 8) sa[d] = (sred[d][0] + sred[d][1] + sred[d][2] + sred[d][3]) * 0.0625f;
    if (d == 0) {
        g1sh = 1.f / (1.f + __expf(-(sg1[0] + sg1[1] + sg1[2] + sg1[3])));
        gateb2[row] = 1.f / (1.f + __expf(-(sg2[0] + sg2[1] + sg2[2] + sg2[3])));
    }
    __syncthreads();
    if (d < 8) {
        float m = sa[0];
        #pragma unroll
        for (int k = 1; k < 8; k++) m = fmaxf(m, sa[k]);
        float e = __expf(sa[d] - m), sum = 0.f;
        #pragma unroll
        for (int k = 0; k < 8; k++) sum += __expf(sa[k] - m);
        wD[(long)row * 8 + d] = g1sh * e / sum;
    }
}

// partial avg + per-chunk weight sums
__global__ __launch_bounds__(256) void wm_avg_partial_k(
    const float* __restrict__ wD, const u16* __restrict__ cw,
    float* __restrict__ part, float* __restrict__ part2)
{
    int blk = blockIdx.x;
    int b = blk >> 6, k = (blk >> 3) & 7, ch = blk & 7;
    int d = threadIdx.x;
    const float* wp = wD + ((long)b * 2048 + ch * 256) * 8 + k;
    const u16*   cp = cw + ((long)b * 2048 + ch * 256) * 1024 + 256 + d;
    float acc = 0.f, wsum = 0.f;
    for (int s = 0; s < 256; s++) {
        float wv = wp[s * 8];
        acc += wv * bf2f(cp[(long)s * 1024]);
        wsum += wv;
    }
    part[(long)blk * 256 + d] = acc;
    if (d == 0) part2[blk] = wsum;
}

__global__ __launch_bounds__(256) void wm_final_k(
    const float* __restrict__ part, const float* __restrict__ part2,
    const float* __restrict__ wm, float* __restrict__ out)
{
    int bk = blockIdx.x;
    int d = threadIdx.x;
    float acc = 0.f, t = 0.f;
    #pragma unroll
    for (int ch = 0; ch < 8; ch++) {
        acc += part[((long)bk * 8 + ch) * 256 + d];
        t   += part2[bk * 8 + ch];
    }
    float alpha = fminf(fmaxf(t, 0.f), 1.f);
    float avg = acc / (t + 1e-6f);
    long base = (long)(bk >> 3) * 2056 + (bk & 7) * 257;
    out[base + d] = (1.f - alpha) * wm[base + d] + alpha * avg;
    if (d == 0) out[base + 256] = fminf(fmaxf(wm[base + 256] + t, 0.f), 1.f);
}

__global__ void colsum_wl_k(const u16* __restrict__ wl, float* __restrict__ totl)
{
    int b = blockIdx.z;
    int n = blockIdx.x * 256 + threadIdx.x;
    int s0 = blockIdx.y * 256;
    const u16* p = wl + ((long)b * 2048 + s0) * 768 + n;
    float acc = 0.f;
    for (int s = 0; s < 256; s++) acc += bf2f(p[(long)s * 768]);
    atomicAdd(&totl[b * 768 + n], acc);
}

// cache blend with fused 4-way split-K combine of bf16 partials
__global__ __launch_bounds__(256) void cache_blend_k(
    const float* __restrict__ cache, const u16* __restrict__ Pp, long pStride,
    const float* __restrict__ totl, float* __restrict__ out)
{
    int i4 = blockIdx.x * 256 + threadIdx.x;   // < 196608
    float s[4] = {0.f, 0.f, 0.f, 0.f};
    #pragma unroll
    for (int k = 0; k < 4; k++) {
        uint2 r = reinterpret_cast<const uint2*>(Pp + (long)k * pStride)[i4];
        float v[4]; unpk4(r, v);
        s[0] += v[0]; s[1] += v[1]; s[2] += v[2]; s[3] += v[3];
    }
    long i = (long)i4 * 4;
    int bn = (int)(i >> 8);
    float t = totl[bn];
    float a = fminf(fmaxf(t, 0.f), 1.f);
    float inv = a / (t + 1e-6f);
    float4 cv = reinterpret_cast<const float4*>(cache)[i4];
    float4 o;
    o.x = (1.f - a) * cv.x + s[0] * inv;
    o.y = (1.f - a) * cv.y + s[1] * inv;
    o.z = (1.f - a) * cv.z + s[2] * inv;
    o.w = (1.f - a) * cv.w + s[3] * inv;
    reinterpret_cast<float4*>(out)[i4] = o;
}

// ---------------------------------------------------------------------------
extern "C" void kernel_launch(void* const* d_in, const int* in_sizes, int n_in,
                              void* d_out, int out_size, void* d_ws, size_t ws_size,
                              hipStream_t stream)
{
    const int D = 1024, DC = 256, NL = 768;
    const long MS = 8192;
    const long SB = 2048;

    const float* x       = (const float*)d_in[0];
    const float* cache   = (const float*)d_in[1];
    const float* wm      = (const float*)d_in[2];
    const float* Wq_ltm  = (const float*)d_in[3];
    const float* Wo_ltm  = (const float*)d_in[4];
    const float* wg_ltm  = (const float*)d_in[5];
    const float* Wq_wm   = (const float*)d_in[6];
    const float* Wo_wm   = (const float*)d_in[7];
    const float* wg_wm   = (const float*)d_in[8];
    const float* conv1_w = (const float*)d_in[9];
    const float* conv1_b = (const float*)d_in[10];
    const float* conv2_w = (const float*)d_in[11];
    const float* conv2_b = (const float*)d_in[12];
    const float* ln_g    = (const float*)d_in[13];
    const float* ln_b    = (const float*)d_in[14];
    const float* Wqw_wm  = (const float*)d_in[15];
    const float* Ww_wm   = (const float*)d_in[16];
    const float* wm_keys = (const float*)d_in[17];
    const float* wgw_wm  = (const float*)d_in[18];
    const float* Wqw_ltm = (const float*)d_in[19];
    const float* Ww_ltm  = (const float*)d_in[20];
    const float* wgw_ltm = (const float*)d_in[21];

    float* out_f     = (float*)d_out;
    float* cache_out = out_f + 8388608;
    float* wm_out    = out_f + 8388608 + 786432;

    char* ws = (char*)d_ws;
    size_t off = 0;
    auto alloc = [&](size_t bytes) -> char* {
        char* p = ws + off;
        off = (off + bytes + 255) & ~(size_t)255;
        return p;
    };
    u16* Wqb     = (u16*)alloc((size_t)D*DC*2);
    u16* WoLt    = (u16*)alloc((size_t)D*DC*2);
    u16* WbigT   = (u16*)alloc((size_t)D*D*2);
    u16* c1wt    = (u16*)alloc((size_t)5*D*D*2);
    u16* c2wt    = (u16*)alloc((size_t)5*D*D*2);
    u16* cache_b = (u16*)alloc((size_t)4*NL*DC*2);
    u16* cache_t = (u16*)alloc((size_t)4*NL*DC*2);
    u16* keys_b  = (u16*)alloc((size_t)8*DC*2);
    u16* WqC     = (u16*)alloc((size_t)4*NL*D*2);
    u16* act0    = (u16*)alloc((size_t)MS*D*2);
    u16* act1    = (u16*)alloc((size_t)MS*D*2);
    u16* xltm    = (u16*)alloc((size_t)MS*D*2);
    u16* xpad1   = (u16*)alloc((size_t)4*2056*1024*2);
    u16* xpad2   = (u16*)alloc((size_t)4*2056*1024*2);
    u16* attnb   = (u16*)alloc((size_t)MS*NL*2);
    u16* readb   = (u16*)alloc((size_t)MS*DC*2);
    u16* Pu      = (u16*)alloc((size_t)16777216*2);
    float* CW    = (float*)alloc((size_t)4*8*D*4);
    float* WC    = (float*)alloc((size_t)4*8*D*4);
    float* gateb = (float*)alloc((size_t)MS*4);
    float* gateb2= (float*)alloc((size_t)MS*4);
    float* wD    = (float*)alloc((size_t)MS*8*4);
    float* totl  = (float*)alloc((size_t)4*NL*4);
    float* part  = (float*)alloc((size_t)256*256*4);
    float* part2 = (float*)alloc((size_t)256*4);
    u16*   qbig   = act0;    // cols: 0 qw | 256 cw | 512 ql | 768 cl

    // ---- mega-prep ----
    prep_k<<<21634, 256, 0, stream>>>(
        x, cache, wm_keys, wm, Wo_wm, Wq_wm,
        Wq_ltm, Wqw_wm, Ww_wm, Wqw_ltm, Ww_ltm, Wo_ltm, conv1_w, conv2_w,
        xpad1, xpad2, totl, act0, cache_b, keys_b,
        Wqb, WbigT, WoLt, c1wt, c2wt, cache_t, CW, WC);

    // ---- Phase A: LTM read ----
    gemm_bf16<0,1,0,128,1,0><<<dim3(6,8,4), 256, 0, stream>>>(
        cache_b, Wqb, nullptr, WqC, nullptr, nullptr,
        768,1024,256, 256,256, 196608L, 0L, 786432L, nullptr, 0, 0);
    gemv_sigmoid_k<<<2048, 256, 0, stream>>>(act0, wg_ltm, gateb);
    gemm_bf16<0,1,0,128,2,1><<<dim3(96,1,8), 256, 0, stream>>>(
        act0, WqC, nullptr, nullptr, nullptr, nullptr,
        2048,768,1024, 1024,1024, SB*1024, 786432L, SB*768, Pu, 6291456L, 6);
    softmax768_k<2><<<8192, 256, 0, stream>>>(Pu, 6291456L, attnb, nullptr);
    gemm_bf16<0,1,0,64,2,1><<<dim3(64,1,8), 256, 0, stream>>>(
        attnb, cache_t, nullptr, nullptr, nullptr, nullptr,
        2048,256,768, 768,768, SB*768, (long)NL*DC, SB*256, Pu, 2097152L, 4);
    ksum_k<2,1><<<2048, 256, 0, stream>>>(Pu, 2097152L, nullptr, readb, 524288);
    gemm_bf16<0,1,6,128,1,1><<<dim3(512,1,1), 256, 0, stream>>>(
        readb, WoLt, nullptr, xltm, (const float*)act0, gateb,
        8192,1024,256, 256,256, 0,0,0, nullptr, 0, 8);

    // ---- Phase B: WM read (bf16 x_ltm, writes padded xpad1 only) ----
    wm_read_fused_k<<<8192, 256, 0, stream>>>(WC, CW, wg_wm, xltm, xpad1);

    // ---- Phase C: convs (interleaved counted-vmcnt, split-K=2) + gelu+LN ----
    conv8_k<1><<<dim3(32,4,2), 512, 0, stream>>>(xpad1, c1wt, Pu, Pu + 8388608);
    gelu_reduce_k<<<8192, 256, 0, stream>>>(Pu, Pu + 8388608, xpad1, conv1_b, xpad2);
    conv8_k<2><<<dim3(32,4,2), 512, 0, stream>>>(xpad2, c2wt, Pu, Pu + 8388608);
    gelu_ln_k<<<8192, 256, 0, stream>>>(
        Pu, Pu + 8388608, xpad2, conv2_b, ln_g, ln_b, out_f, act1);

    // ---- Phase D: all four write-projections in one GEMM (swizzled) ----
    gemm_bf16<0,1,0,128,1,1><<<dim3(512,1,1), 256, 0, stream>>>(
        act1, WbigT, nullptr, qbig, nullptr, nullptr,
        8192,1024,1024, 1024,1024, 0,0,0, nullptr, 0, 8);
    attn8_wg_k<<<8192, 256, 0, stream>>>(qbig, act1, wgw_wm, wgw_ltm, keys_b, wD, gateb2);
    wm_avg_partial_k<<<256, 256, 0, stream>>>(wD, qbig, part, part2);
    wm_final_k<<<32, 256, 0, stream>>>(part, part2, wm, wm_out);

    // ---- Phase E: LTM write ----
    gemm_bf16<0,1,0,128,1,1><<<dim3(96,1,4), 256, 0, stream>>>(
        qbig + 512, cache_b, nullptr, Pu, nullptr, nullptr,
        2048,768,256, 1024,256, SB*1024, (long)NL*DC, SB*768, nullptr, 0, 6);
    softmax768_k<1><<<8192, 256, 0, stream>>>(Pu, 0L, attnb, gateb2);
    colsum_wl_k<<<dim3(3, 8, 4), 256, 0, stream>>>(attnb, totl);
    gemm_bf16<1,0,1,64,4,0><<<dim3(6,4,16), 256, 0, stream>>>(
        attnb, qbig + 768, nullptr, nullptr, nullptr, nullptr,
        768,256,2048, 768,1024, SB*768, SB*1024, 196608L, Pu, 786432L, 0);
    cache_blend_k<<<768, 256, 0, stream>>>(cache, Pu, 786432L, totl, cache_out);

    (void)in_sizes; (void)n_in; (void)out_size; (void)ws_size;
}